// Round 13
// baseline (50.961 us; speedup 1.0000x reference)
//
#include <hip/hip_runtime.h>

// VectorQuantizer, round 13: R10 geometry + intra-block pipeline: 512 blocks x
// 2 consecutive 128-row tiles, double-buffered X LDS, tile-1 loads prefetched
// under tile-0 compute, NT stores drain under next stage. E groups reloaded
// (32 VGPR), per-rt argmin reduce with keysS min-merge across groups.
// inputs: in [32,64,64,64] fp32 NCHW, emb [512,64] fp32.
// out[0:8388608] = quantized NCHW, out[8388608] = loss.
// ws: [0,65536)B emb bf16; [65536,+2048) npm = -0.5*(1+||e||^2); [67584,+2048) partials.

#define D 64
#define K_EMB 512
#define HW 4096
#define CHW (D * HW)
#define OUT_ELEMS 8388608
#define NB_MAIN 512 // 1024 tiles / 2 per block
#define SWZ(r) ((((r) ^ ((r) >> 2))) & 7)

typedef __attribute__((ext_vector_type(8))) short short8;
typedef __attribute__((ext_vector_type(4))) float f32x4;

__device__ __forceinline__ unsigned short f2bf(float f) {
    unsigned u = __float_as_uint(f);
    u += 0x7FFFu + ((u >> 16) & 1u); // RNE
    return (unsigned short)(u >> 16);
}
__device__ __forceinline__ float bf2f(unsigned short h) {
    return __uint_as_float(((unsigned)h) << 16);
}
__device__ __forceinline__ unsigned umin32(unsigned a, unsigned b) { return a <= b ? a : b; }
// RNE f32->bf16 pair pack: d.lo = bf16(lo), d.hi = bf16(hi).
__device__ __forceinline__ unsigned cvtpk(float lo, float hi) {
    unsigned r;
    asm("v_cvt_pk_bf16_f32 %0, %1, %2" : "=v"(r) : "v"(lo), "v"(hi));
    return r;
}

// Prep: codebook fp32 -> bf16 rows + npm = -0.5*(1+||e||^2).
__global__ void vq_prep(const float* __restrict__ emb, unsigned short* __restrict__ ebf,
                        float* __restrict__ npm) {
    int k = blockIdx.x * 256 + threadIdx.x; // <<<2,256>>>
    const float4* e4 = reinterpret_cast<const float4*>(emb + k * D);
    unsigned short h[D];
    float acc = 0.f;
#pragma unroll
    for (int i = 0; i < 16; ++i) {
        float4 v = e4[i];
        acc += v.x * v.x + v.y * v.y + v.z * v.z + v.w * v.w;
        h[4 * i + 0] = f2bf(v.x); h[4 * i + 1] = f2bf(v.y);
        h[4 * i + 2] = f2bf(v.z); h[4 * i + 3] = f2bf(v.w);
    }
    npm[k] = -0.5f * (1.0f + acc);
    uint4* dst = reinterpret_cast<uint4*>(ebf + k * D);
#pragma unroll
    for (int i = 0; i < 8; ++i) {
        uint4 p;
        p.x = (unsigned)h[8 * i + 0] | ((unsigned)h[8 * i + 1] << 16);
        p.y = (unsigned)h[8 * i + 2] | ((unsigned)h[8 * i + 3] << 16);
        p.z = (unsigned)h[8 * i + 4] | ((unsigned)h[8 * i + 5] << 16);
        p.w = (unsigned)h[8 * i + 6] | ((unsigned)h[8 * i + 7] << 16);
        dst[i] = p;
    }
}

__global__ __launch_bounds__(256, 2) void vq_mfma(const float* __restrict__ in,
                                                  const unsigned short* __restrict__ ebf,
                                                  const float* __restrict__ npm,
                                                  const float* __restrict__ emb,
                                                  float* __restrict__ out,
                                                  float* __restrict__ partials) {
    __shared__ __align__(16) char ldsX[2][16384]; // 2 x (128 rows x 128B), swizzled
    __shared__ __align__(16) unsigned keysS[4][128];
    __shared__ float red4[4];

    const int tid = threadIdx.x;
    const int lane = tid & 63;
    const int w = tid >> 6;
    const int col = lane & 15;
    const int dg = lane >> 4;
    // Bijective XCD swizzle (512 % 8 == 0). Tiles bid*2, bid*2+1 are adjacent
    // in hw -> effective 1KB DRAM chunks per channel per block.
    const int bid = ((blockIdx.x & 7) << 6) | (blockIdx.x >> 3);

    const int rw = (tid & 31) * 4; // staged rows rw..rw+3
    const int cg = tid >> 5;       // staged channel group (8 channels)

    float lsum_all = 0.f;

    // ---- prologue: issue tile-0 input loads ----
    f32x4 v[8];
    {
        const int tt = bid * 2;
        const float* xb = in + (tt >> 5) * CHW + cg * 8 * HW + ((tt & 31) << 7) + rw;
#pragma unroll
        for (int ch = 0; ch < 8; ++ch)
            v[ch] = *reinterpret_cast<const f32x4*>(xb + ch * HW);
    }

    const short8* e8 = reinterpret_cast<const short8*>(ebf);

#pragma unroll 1
    for (int tn = 0; tn < 2; ++tn) {
        const int tt = bid * 2 + tn;
        const int n = tt >> 5;
        const int hw0 = (tt & 31) << 7;
        char* X = ldsX[tn];

        // ---- stage tile tn from v regs: cvtpk + swizzled ds_write ----
#pragma unroll
        for (int j = 0; j < 4; ++j) {
            const int r = rw + j;
            uint4 p;
            p.x = cvtpk(v[0][j], v[1][j]);
            p.y = cvtpk(v[2][j], v[3][j]);
            p.z = cvtpk(v[4][j], v[5][j]);
            p.w = cvtpk(v[6][j], v[7][j]);
            *reinterpret_cast<uint4*>(X + r * 128 + ((cg ^ SWZ(r)) * 16)) = p;
        }
        // ---- prefetch tile tn+1 (in flight under this tile's compute) ----
        if (tn == 0) {
            const int t2 = tt + 1;
            const float* xb2 = in + (t2 >> 5) * CHW + cg * 8 * HW + ((t2 & 31) << 7) + rw;
#pragma unroll
            for (int ch = 0; ch < 8; ++ch)
                v[ch] = *reinterpret_cast<const f32x4*>(xb2 + ch * HW);
        }
        __syncthreads();

        // ---- compute: 2 code-groups of 64; ef regs (32 VGPR) reused ----
#pragma unroll 1
        for (int g = 0; g < 2; ++g) {
            const int kb = w * 128 + g * 64 + col;
            short8 ef[4][2];
            float npv[4];
#pragma unroll
            for (int ct = 0; ct < 4; ++ct) {
                const int k = kb + ct * 16;
                ef[ct][0] = e8[k * 8 + dg];
                ef[ct][1] = e8[k * 8 + 4 + dg];
                npv[ct] = npm[k];
            }
#pragma unroll
            for (int rt = 0; rt < 8; ++rt) {
                const int row = rt * 16 + col;
                short8 a0 = *reinterpret_cast<const short8*>(
                    X + row * 128 + ((dg ^ SWZ(row)) * 16));
                short8 a1 = *reinterpret_cast<const short8*>(
                    X + row * 128 + (((4 + dg) ^ SWZ(row)) * 16));
                unsigned best[4] = {0xFFFFFFFFu, 0xFFFFFFFFu, 0xFFFFFFFFu, 0xFFFFFFFFu};
#pragma unroll
                for (int ct = 0; ct < 4; ++ct) {
                    // acc = x.e - 0.5*(1+||e||^2) = -crit/2 < 0; among negatives
                    // the smallest uint is the least-negative float = min crit.
                    f32x4 acc = {npv[ct], npv[ct], npv[ct], npv[ct]};
                    acc = __builtin_amdgcn_mfma_f32_16x16x32_bf16(a0, ef[ct][0], acc, 0, 0, 0);
                    acc = __builtin_amdgcn_mfma_f32_16x16x32_bf16(a1, ef[ct][1], acc, 0, 0, 0);
                    const unsigned kc = (unsigned)(kb + ct * 16);
#pragma unroll
                    for (int i = 0; i < 4; ++i) {
                        unsigned key = (__float_as_uint(acc[i]) & 0xFFFFFE00u) | kc;
                        best[i] = umin32(best[i], key);
                    }
                }
                // per-row reduce across 16 code-columns; min-merge groups in LDS
#pragma unroll
                for (int i = 0; i < 4; ++i) {
                    unsigned k = best[i];
#pragma unroll
                    for (int s = 1; s < 16; s <<= 1)
                        k = umin32(k, (unsigned)__shfl_xor((int)k, s, 64));
                    if (col == 0) {
                        unsigned* slot = &keysS[w][rt * 16 + dg * 4 + i];
                        *slot = g == 0 ? k : umin32(*slot, k);
                    }
                }
            }
        }
        __syncthreads();

        // ---- epilogue: thread owns 4 rows x 8 channels; merge waves ----
        const int rg = tid & 31;
        const int cs = tid >> 5;
        uint4 q0 = *reinterpret_cast<const uint4*>(&keysS[0][rg * 4]);
        uint4 q1 = *reinterpret_cast<const uint4*>(&keysS[1][rg * 4]);
        uint4 q2 = *reinterpret_cast<const uint4*>(&keysS[2][rg * 4]);
        uint4 q3 = *reinterpret_cast<const uint4*>(&keysS[3][rg * 4]);
        int kk[4];
        kk[0] = (int)(umin32(umin32(q0.x, q1.x), umin32(q2.x, q3.x)) & 511u);
        kk[1] = (int)(umin32(umin32(q0.y, q1.y), umin32(q2.y, q3.y)) & 511u);
        kk[2] = (int)(umin32(umin32(q0.z, q1.z), umin32(q2.z, q3.z)) & 511u);
        kk[3] = (int)(umin32(umin32(q0.w, q1.w), umin32(q2.w, q3.w)) & 511u);
        float ej[4][8];
#pragma unroll
        for (int j = 0; j < 4; ++j) {
            const f32x4* ep = reinterpret_cast<const f32x4*>(emb + kk[j] * D + cs * 8);
            *reinterpret_cast<f32x4*>(&ej[j][0]) = ep[0];
            *reinterpret_cast<f32x4*>(&ej[j][4]) = ep[1];
        }
#pragma unroll
        for (int j = 0; j < 4; ++j) {
            const int r = rg * 4 + j;
            short8 x8 = *reinterpret_cast<const short8*>(
                X + r * 128 + ((cs ^ SWZ(r)) * 16));
#pragma unroll
            for (int t = 0; t < 8; ++t) {
                float d = ej[j][t] - bf2f((unsigned short)x8[t]);
                lsum_all = fmaf(d, d, lsum_all);
            }
        }
        float* obase = out + n * CHW + hw0 + rg * 4;
#pragma unroll
        for (int t = 0; t < 8; ++t) {
            f32x4 st = {ej[0][t], ej[1][t], ej[2][t], ej[3][t]};
            __builtin_nontemporal_store(st, reinterpret_cast<f32x4*>(obase + (cs * 8 + t) * HW));
        }
    }

    // ---- loss partial over both tiles (plain store; separate finalize) ----
#pragma unroll
    for (int s = 1; s < 64; s <<= 1) lsum_all += __shfl_xor(lsum_all, s, 64);
    if (lane == 0) red4[w] = lsum_all;
    __syncthreads();
    if (tid == 0) partials[bid] = red4[0] + red4[1] + red4[2] + red4[3];
}

__global__ void vq_finalize(const float* __restrict__ partials, float* __restrict__ loss) {
    __shared__ float s[256];
    float a = 0.f;
    for (int i = threadIdx.x; i < NB_MAIN; i += 256) a += partials[i];
    s[threadIdx.x] = a;
    __syncthreads();
    for (int t = 128; t > 0; t >>= 1) {
        if ((int)threadIdx.x < t) s[threadIdx.x] += s[threadIdx.x + t];
        __syncthreads();
    }
    if (threadIdx.x == 0) loss[0] = 1.25f * s[0] * (1.0f / (float)OUT_ELEMS);
}

extern "C" void kernel_launch(void* const* d_in, const int* in_sizes, int n_in,
                              void* d_out, int out_size, void* d_ws, size_t ws_size,
                              hipStream_t stream) {
    const float* in = (const float*)d_in[0];
    const float* emb = (const float*)d_in[1];
    float* out = (float*)d_out;
    unsigned short* ebf = (unsigned short*)d_ws;
    float* npm = (float*)((char*)d_ws + 65536);
    float* partials = (float*)((char*)d_ws + 67584);

    vq_prep<<<2, 256, 0, stream>>>(emb, ebf, npm);
    vq_mfma<<<NB_MAIN, 256, 0, stream>>>(in, ebf, npm, emb, out, partials);
    vq_finalize<<<1, 256, 0, stream>>>(partials, out + OUT_ELEMS);
}

// Round 14
// 48.715 us; speedup vs baseline: 1.0461x; 1.0461x over previous
//
#include <hip/hip_runtime.h>

// VectorQuantizer, round 14: two-pass. K1 (R10 main minus out-stores) computes
// argmin + loss partials, writes u16 idx. K2 writes the quantized output with
// fully CONTIGUOUS NT stores (block = n x 8-ch group x half-plane, codebook
// column slice in LDS), and block 0 of K2 folds the loss finalize.
// inputs: in [32,64,64,64] fp32 NCHW, emb [512,64] fp32.
// out[0:8388608] = quantized NCHW, out[8388608] = loss.
// ws: [0,65536) ebf bf16; [65536,+2048) npm; [67584,+4096) partials;
//     [71680 -> align 16 @ 71680? use 73728,+262144) idx u16.

#define D 64
#define K_EMB 512
#define HW 4096
#define CHW (D * HW)
#define OUT_ELEMS 8388608
#define NB_MAIN 1024 // 131072 rows / 128 rows per block
#define SWZ(r) ((((r) ^ ((r) >> 2))) & 7)

typedef __attribute__((ext_vector_type(8))) short short8;
typedef __attribute__((ext_vector_type(4))) float f32x4;
typedef __attribute__((ext_vector_type(4))) unsigned short us4;

__device__ __forceinline__ unsigned short f2bf(float f) {
    unsigned u = __float_as_uint(f);
    u += 0x7FFFu + ((u >> 16) & 1u); // RNE
    return (unsigned short)(u >> 16);
}
__device__ __forceinline__ float bf2f(unsigned short h) {
    return __uint_as_float(((unsigned)h) << 16);
}
__device__ __forceinline__ unsigned umin32(unsigned a, unsigned b) { return a <= b ? a : b; }
// RNE f32->bf16 pair pack.
__device__ __forceinline__ unsigned cvtpk(float lo, float hi) {
    unsigned r;
    asm("v_cvt_pk_bf16_f32 %0, %1, %2" : "=v"(r) : "v"(lo), "v"(hi));
    return r;
}

// Prep: codebook fp32 -> bf16 rows + npm = -0.5*(1+||e||^2).
__global__ void vq_prep(const float* __restrict__ emb, unsigned short* __restrict__ ebf,
                        float* __restrict__ npm) {
    int k = blockIdx.x * 256 + threadIdx.x; // <<<2,256>>>
    const float4* e4 = reinterpret_cast<const float4*>(emb + k * D);
    unsigned short h[D];
    float acc = 0.f;
#pragma unroll
    for (int i = 0; i < 16; ++i) {
        float4 v = e4[i];
        acc += v.x * v.x + v.y * v.y + v.z * v.z + v.w * v.w;
        h[4 * i + 0] = f2bf(v.x); h[4 * i + 1] = f2bf(v.y);
        h[4 * i + 2] = f2bf(v.z); h[4 * i + 3] = f2bf(v.w);
    }
    npm[k] = -0.5f * (1.0f + acc);
    uint4* dst = reinterpret_cast<uint4*>(ebf + k * D);
#pragma unroll
    for (int i = 0; i < 8; ++i) {
        uint4 p;
        p.x = (unsigned)h[8 * i + 0] | ((unsigned)h[8 * i + 1] << 16);
        p.y = (unsigned)h[8 * i + 2] | ((unsigned)h[8 * i + 3] << 16);
        p.z = (unsigned)h[8 * i + 4] | ((unsigned)h[8 * i + 5] << 16);
        p.w = (unsigned)h[8 * i + 6] | ((unsigned)h[8 * i + 7] << 16);
        dst[i] = p;
    }
}

// K1: argmin + loss partials + idx (u16 per pixel). R10 main minus out-stores.
__global__ __launch_bounds__(256, 4) void vq_argmin(const float* __restrict__ in,
                                                    const unsigned short* __restrict__ ebf,
                                                    const float* __restrict__ npm,
                                                    const float* __restrict__ emb,
                                                    unsigned short* __restrict__ idxb,
                                                    float* __restrict__ partials) {
    __shared__ __align__(16) char ldsX[16384]; // 128 rows x 128B bf16, swizzled
    __shared__ __align__(16) unsigned keysS[4][128];
    __shared__ float red4[4];

    const int tid = threadIdx.x;
    const int lane = tid & 63;
    const int w = tid >> 6;
    const int col = lane & 15;
    const int dg = lane >> 4;
    const int bid = ((blockIdx.x & 7) << 7) | (blockIdx.x >> 3); // XCD swizzle
    const int n = bid >> 5;
    const int hw0 = (bid & 31) << 7;

    // ---- stage X: thread owns 4 rows x 8 channels; dwordx4 loads + cvt_pk ----
    {
        const int rw = (tid & 31) * 4;
        const int cg = tid >> 5;
        const float* xb = in + n * CHW + cg * 8 * HW + hw0 + rw;
        f32x4 v[8];
#pragma unroll
        for (int ch = 0; ch < 8; ++ch)
            v[ch] = *reinterpret_cast<const f32x4*>(xb + ch * HW);
#pragma unroll
        for (int j = 0; j < 4; ++j) {
            const int r = rw + j;
            uint4 p;
            p.x = cvtpk(v[0][j], v[1][j]);
            p.y = cvtpk(v[2][j], v[3][j]);
            p.z = cvtpk(v[4][j], v[5][j]);
            p.w = cvtpk(v[6][j], v[7][j]);
            *reinterpret_cast<uint4*>(ldsX + r * 128 + ((cg ^ SWZ(r)) * 16)) = p;
        }
    }

    unsigned best[8][4];
#pragma unroll
    for (int rt = 0; rt < 8; ++rt)
#pragma unroll
        for (int i = 0; i < 4; ++i) best[rt][i] = 0xFFFFFFFFu;

    const short8* e8 = reinterpret_cast<const short8*>(ebf);
#pragma unroll 1
    for (int g = 0; g < 2; ++g) {
        const int kb = w * 128 + g * 64 + col;
        short8 ef[4][2];
        float npv[4];
#pragma unroll
        for (int ct = 0; ct < 4; ++ct) {
            const int k = kb + ct * 16;
            ef[ct][0] = e8[k * 8 + dg];
            ef[ct][1] = e8[k * 8 + 4 + dg];
            npv[ct] = npm[k];
        }
        if (g == 0) __syncthreads();

#pragma unroll
        for (int rt = 0; rt < 8; ++rt) {
            const int row = rt * 16 + col;
            short8 a0 = *reinterpret_cast<const short8*>(
                ldsX + row * 128 + ((dg ^ SWZ(row)) * 16));
            short8 a1 = *reinterpret_cast<const short8*>(
                ldsX + row * 128 + (((4 + dg) ^ SWZ(row)) * 16));
#pragma unroll
            for (int ct = 0; ct < 4; ++ct) {
                // acc = x.e - 0.5*(1+||e||^2) = -crit/2 < 0
                f32x4 acc = {npv[ct], npv[ct], npv[ct], npv[ct]};
                acc = __builtin_amdgcn_mfma_f32_16x16x32_bf16(a0, ef[ct][0], acc, 0, 0, 0);
                acc = __builtin_amdgcn_mfma_f32_16x16x32_bf16(a1, ef[ct][1], acc, 0, 0, 0);
                const unsigned kc = (unsigned)(kb + ct * 16);
#pragma unroll
                for (int i = 0; i < 4; ++i) {
                    unsigned key = (__float_as_uint(acc[i]) & 0xFFFFFE00u) | kc;
                    best[rt][i] = umin32(best[rt][i], key);
                }
            }
        }
    }

#pragma unroll
    for (int rt = 0; rt < 8; ++rt)
#pragma unroll
        for (int i = 0; i < 4; ++i) {
            unsigned k = best[rt][i];
#pragma unroll
            for (int s = 1; s < 16; s <<= 1)
                k = umin32(k, (unsigned)__shfl_xor((int)k, s, 64));
            if (col == 0) keysS[w][rt * 16 + dg * 4 + i] = k;
        }
    __syncthreads();

    // ---- epilogue: merge waves; write idx; loss from fp32 emb gather ----
    const int rg = tid & 31;
    const int cs = tid >> 5;
    uint4 q0 = *reinterpret_cast<const uint4*>(&keysS[0][rg * 4]);
    uint4 q1 = *reinterpret_cast<const uint4*>(&keysS[1][rg * 4]);
    uint4 q2 = *reinterpret_cast<const uint4*>(&keysS[2][rg * 4]);
    uint4 q3 = *reinterpret_cast<const uint4*>(&keysS[3][rg * 4]);
    int kk[4];
    kk[0] = (int)(umin32(umin32(q0.x, q1.x), umin32(q2.x, q3.x)) & 511u);
    kk[1] = (int)(umin32(umin32(q0.y, q1.y), umin32(q2.y, q3.y)) & 511u);
    kk[2] = (int)(umin32(umin32(q0.z, q1.z), umin32(q2.z, q3.z)) & 511u);
    kk[3] = (int)(umin32(umin32(q0.w, q1.w), umin32(q2.w, q3.w)) & 511u);
    if (cs == 0) {
        us4 iv = {(unsigned short)kk[0], (unsigned short)kk[1],
                  (unsigned short)kk[2], (unsigned short)kk[3]};
        *reinterpret_cast<us4*>(idxb + bid * 128 + rg * 4) = iv;
    }
    float ej[4][8];
#pragma unroll
    for (int j = 0; j < 4; ++j) {
        const f32x4* ep = reinterpret_cast<const f32x4*>(emb + kk[j] * D + cs * 8);
        *reinterpret_cast<f32x4*>(&ej[j][0]) = ep[0];
        *reinterpret_cast<f32x4*>(&ej[j][4]) = ep[1];
    }
    float lsum = 0.f;
#pragma unroll
    for (int j = 0; j < 4; ++j) {
        const int r = rg * 4 + j;
        short8 x8 = *reinterpret_cast<const short8*>(
            ldsX + r * 128 + ((cs ^ SWZ(r)) * 16));
#pragma unroll
        for (int t = 0; t < 8; ++t) {
            float d = ej[j][t] - bf2f((unsigned short)x8[t]);
            lsum = fmaf(d, d, lsum);
        }
    }
#pragma unroll
    for (int s = 1; s < 64; s <<= 1) lsum += __shfl_xor(lsum, s, 64);
    if (lane == 0) red4[w] = lsum;
    __syncthreads();
    if (tid == 0) partials[bid] = red4[0] + red4[1] + red4[2] + red4[3];
}

// K2: contiguous writer. Block = (n, 8-ch group, half-plane of 2048 px).
// Stages emb[:, cg*8..+8) in LDS (16 KB), gathers per-pixel rows, NT-stores
// contiguous f32x4 runs. Block 0 also reduces the loss partials (deterministic).
__global__ __launch_bounds__(256, 4) void vq_scatter(const float* __restrict__ emb,
                                                     const unsigned short* __restrict__ idxb,
                                                     const float* __restrict__ partials,
                                                     float* __restrict__ out) {
    __shared__ __align__(16) float eC[K_EMB][8]; // codebook column slice
    __shared__ float fin[256];

    const int tid = threadIdx.x;
    const int bid = blockIdx.x;        // 512 blocks
    const int n = bid >> 4;            // image
    const int cg = (bid >> 1) & 7;     // channel group (8 channels)
    const int half = bid & 1;          // half-plane

    // stage codebook slice: thread t covers codes t and t+256
#pragma unroll
    for (int q = 0; q < 2; ++q) {
        const int k = tid + q * 256;
        f32x4 a = *reinterpret_cast<const f32x4*>(emb + k * D + cg * 8);
        f32x4 b = *reinterpret_cast<const f32x4*>(emb + k * D + cg * 8 + 4);
        *reinterpret_cast<f32x4*>(&eC[k][0]) = a;
        *reinterpret_cast<f32x4*>(&eC[k][4]) = b;
    }
    __syncthreads();

    // this thread's 8 consecutive pixels
    const int px0 = half * 2048 + tid * 8;
    us4 i01 = *reinterpret_cast<const us4*>(idxb + n * HW + px0);
    us4 i23 = *reinterpret_cast<const us4*>(idxb + n * HW + px0 + 4);
    float vv[8][8]; // [pixel][channel]
#pragma unroll
    for (int p = 0; p < 4; ++p) {
        const int k = (int)i01[p];
        *reinterpret_cast<f32x4*>(&vv[p][0]) = *reinterpret_cast<const f32x4*>(&eC[k][0]);
        *reinterpret_cast<f32x4*>(&vv[p][4]) = *reinterpret_cast<const f32x4*>(&eC[k][4]);
    }
#pragma unroll
    for (int p = 0; p < 4; ++p) {
        const int k = (int)i23[p];
        *reinterpret_cast<f32x4*>(&vv[4 + p][0]) = *reinterpret_cast<const f32x4*>(&eC[k][0]);
        *reinterpret_cast<f32x4*>(&vv[4 + p][4]) = *reinterpret_cast<const f32x4*>(&eC[k][4]);
    }
    float* ob = out + n * CHW + cg * 8 * HW + px0;
#pragma unroll
    for (int c = 0; c < 8; ++c) {
        f32x4 s0 = {vv[0][c], vv[1][c], vv[2][c], vv[3][c]};
        f32x4 s1 = {vv[4][c], vv[5][c], vv[6][c], vv[7][c]};
        __builtin_nontemporal_store(s0, reinterpret_cast<f32x4*>(ob + c * HW));
        __builtin_nontemporal_store(s1, reinterpret_cast<f32x4*>(ob + c * HW + 4));
    }

    // block 0: fold the loss finalize (deterministic tree reduce)
    if (bid == 0) {
        float a = 0.f;
#pragma unroll
        for (int i = 0; i < 4; ++i) a += partials[tid + 256 * i];
        fin[tid] = a;
        __syncthreads();
        for (int t = 128; t > 0; t >>= 1) {
            if (tid < t) fin[tid] += fin[tid + t];
            __syncthreads();
        }
        if (tid == 0) out[OUT_ELEMS] = 1.25f * fin[0] * (1.0f / (float)OUT_ELEMS);
    }
}

extern "C" void kernel_launch(void* const* d_in, const int* in_sizes, int n_in,
                              void* d_out, int out_size, void* d_ws, size_t ws_size,
                              hipStream_t stream) {
    const float* in = (const float*)d_in[0];
    const float* emb = (const float*)d_in[1];
    float* out = (float*)d_out;
    unsigned short* ebf = (unsigned short*)d_ws;
    float* npm = (float*)((char*)d_ws + 65536);
    float* partials = (float*)((char*)d_ws + 67584);
    unsigned short* idxb = (unsigned short*)((char*)d_ws + 73728);

    vq_prep<<<2, 256, 0, stream>>>(emb, ebf, npm);
    vq_argmin<<<NB_MAIN, 256, 0, stream>>>(in, ebf, npm, emb, idxb, partials);
    vq_scatter<<<512, 256, 0, stream>>>(emb, idxb, partials, out);
}